// Round 1
// baseline (1006.825 us; speedup 1.0000x reference)
//
#include <hip/hip_runtime.h>

typedef unsigned short u16;
typedef __attribute__((ext_vector_type(4))) float f32x4;
typedef __attribute__((ext_vector_type(8))) short bf16x8;
typedef __attribute__((ext_vector_type(8))) unsigned short u16x8;
typedef __attribute__((ext_vector_type(4))) unsigned short u16x4;

__device__ __forceinline__ u16 f2bf(float f) {
  union { float f; unsigned u; } v; v.f = f;
  unsigned r = v.u + 0x7FFFu + ((v.u >> 16) & 1u);
  return (u16)(r >> 16);
}
__device__ __forceinline__ float bf2f(u16 h) {
  union { unsigned u; float f; } v; v.u = ((unsigned)h) << 16; return v.f;
}

__device__ __forceinline__ void gload_lds16(const void* g, void* l) {
  __builtin_amdgcn_global_load_lds((const __attribute__((address_space(1))) void*)g,
                                   (__attribute__((address_space(3))) void*)l, 16, 0, 0);
}

// ---------------- prep kernels ----------------

__global__ void k_zero(u16x8* __restrict__ p, int n8) {
  int i = blockIdx.x * blockDim.x + threadIdx.x;
  int stride = gridDim.x * blockDim.x;
  u16x8 z = (u16x8)0;
  for (; i < n8; i += stride) p[i] = z;
}

__global__ void k_cvt_x(const float* __restrict__ in, u16* __restrict__ out, int n4) {
  int i = blockIdx.x * blockDim.x + threadIdx.x;
  int stride = gridDim.x * blockDim.x;
  const f32x4* in4 = (const f32x4*)in;
  u16x4* out4 = (u16x4*)out;
  for (; i < n4; i += stride) {
    f32x4 v = in4[i];
    u16x4 o;
    o[0] = f2bf(v[0]); o[1] = f2bf(v[1]); o[2] = f2bf(v[2]); o[3] = f2bf(v[3]);
    out4[i] = o;
  }
}

// w [K][N] f32 -> outT [N][2K] bf16: rows n, cols 0..K-1 = hi, K..2K-1 = lo
__global__ void k_split_w(const float* __restrict__ w, u16* __restrict__ outT, int K, int N) {
  int i = blockIdx.x * blockDim.x + threadIdx.x;
  int total = K * N;
  int stride = gridDim.x * blockDim.x;
  for (; i < total; i += stride) {
    int k = i / N, n = i - k * N;
    float f = w[i];
    u16 hi = f2bf(f);
    u16 lo = f2bf(f - bf2f(hi));
    size_t o = (size_t)n * (2 * K) + k;
    outT[o] = hi;
    outT[o + K] = lo;
  }
}

// y [1232][768] f32 -> yb [1232][1536] bf16 (columns duplicated)
__global__ void k_prep_y(const float* __restrict__ y, u16* __restrict__ yb) {
  int i = blockIdx.x * blockDim.x + threadIdx.x;
  int total = 1232 * 1536;
  int stride = gridDim.x * blockDim.x;
  for (; i < total; i += stride) {
    int m = i / 1536, k = i - m * 1536;
    int ks = (k < 768) ? k : k - 768;
    yb[i] = f2bf(y[m * 768 + ks]);
  }
}

// ---------------- main GEMM ----------------
// C[m,n] = sum_k A[m, (k & akmask_or_k)] * B[n][k]  (B pre-transposed [N=1024][Kdim])
// EPI 0: +bias, bf16 -> out[m*1024+n]        (Q projection)
// EPI 1: +bias, f32  -> out[m*1024+n]        (final output)
// EPI 2: +bias, bf16 -> KT[b][h][96 s][64 d] (K, natural, m=b*77+s, n=h*64+d)
// EPI 3: +bias, bf16 -> VT[b][h][64 d][96 s] (V, transposed)
template <int EPI>
__global__ __launch_bounds__(256, 2) void gemm_bf16(
    const u16* __restrict__ A, const u16* __restrict__ B,
    const float* __restrict__ bias, void* __restrict__ outp,
    int M, int Kdim, int lda, int akmask)
{
  __shared__ u16 sA[128 * 32];
  __shared__ u16 sB[128 * 32];
  const int t = threadIdx.x;
  const int ntiles = 8; // N = 1024
  const int bm = blockIdx.x / ntiles, bn = blockIdx.x % ntiles;
  const int m0 = bm * 128, n0 = bn * 128;
  const int l = t & 63, wv_ = t >> 6;
  const int lr = l & 15, lg = l >> 4;
  const int wm = (wv_ >> 1) * 64, wn = (wv_ & 1) * 64;

  // staging geometry: thread t covers LDS linear bytes t*16 (+ issue*4096)
  const int srow = t >> 2;                              // row within 64-row half
  const int ssw = ((t >> 2) & 3) ^ ((t >> 4) & 3);      // slot swizzle
  const int scol = ((t & 3) ^ ssw) * 8;                 // swizzled k-element offset
  char* ldsA = (char*)sA;
  char* ldsB = (char*)sB;
  const int ldsoff = wv_ * 1024;                        // wave-uniform base

  // read-side swizzle
  const int swl = (lr & 3) ^ ((lr >> 2) & 3);
  const int rds = (lg ^ swl) * 8;

  f32x4 acc[4][4] = {};

  const int kiter = Kdim / 32;
  for (int kt = 0; kt < kiter; ++kt) {
    const int k0 = kt * 32;
    const int ak0 = k0 & akmask;
    __syncthreads();
    {
      int r1 = m0 + srow;       if (r1 > M - 1) r1 = M - 1;
      int r2 = m0 + 64 + srow;  if (r2 > M - 1) r2 = M - 1;
      gload_lds16(A + (size_t)r1 * lda + ak0 + scol, ldsA + 0    + ldsoff);
      gload_lds16(A + (size_t)r2 * lda + ak0 + scol, ldsA + 4096 + ldsoff);
      gload_lds16(B + (size_t)(n0 + srow) * Kdim + k0 + scol,      ldsB + 0    + ldsoff);
      gload_lds16(B + (size_t)(n0 + 64 + srow) * Kdim + k0 + scol, ldsB + 4096 + ldsoff);
    }
    __syncthreads();
    bf16x8 af[4], bf[4];
#pragma unroll
    for (int mt = 0; mt < 4; ++mt)
      af[mt] = *(const bf16x8*)&sA[(wm + mt * 16 + lr) * 32 + rds];
#pragma unroll
    for (int nt = 0; nt < 4; ++nt)
      bf[nt] = *(const bf16x8*)&sB[(wn + nt * 16 + lr) * 32 + rds];
#pragma unroll
    for (int mt = 0; mt < 4; ++mt)
#pragma unroll
      for (int nt = 0; nt < 4; ++nt)
        acc[mt][nt] = __builtin_amdgcn_mfma_f32_16x16x32_bf16(af[mt], bf[nt], acc[mt][nt], 0, 0, 0);
  }

  // epilogue: C row = wm+mt*16+lg*4+r, col = wn+nt*16+lr
#pragma unroll
  for (int mt = 0; mt < 4; ++mt) {
#pragma unroll
    for (int nt = 0; nt < 4; ++nt) {
      const int gc = n0 + wn + nt * 16 + lr;
      const float bb = bias[gc];
#pragma unroll
      for (int r = 0; r < 4; ++r) {
        const int gr = m0 + wm + mt * 16 + lg * 4 + r;
        const float v = acc[mt][nt][r] + bb;
        if constexpr (EPI == 0) {
          ((u16*)outp)[(size_t)gr * 1024 + gc] = f2bf(v);
        } else if constexpr (EPI == 1) {
          ((float*)outp)[(size_t)gr * 1024 + gc] = v;
        } else if constexpr (EPI == 2) {
          if (gr < M) {
            int bb2 = gr / 77, s = gr - bb2 * 77;
            int hh = gc >> 6, d = gc & 63;
            ((u16*)outp)[(((size_t)bb2 * 16 + hh) * 96 + s) * 64 + d] = f2bf(v);
          }
        } else {
          if (gr < M) {
            int bb2 = gr / 77, s = gr - bb2 * 77;
            int hh = gc >> 6, d = gc & 63;
            ((u16*)outp)[(((size_t)bb2 * 16 + hh) * 64 + d) * 96 + s] = f2bf(v);
          }
        }
      }
    }
  }
}

// ---------------- fused attention ----------------
// KT [B][H][96 s][64 d] bf16 (rows>=77 zero), VT [B][H][64 d][96 s] bf16 (cols>=77 zero)
// QB [65536][1024] bf16: read q, write attn-out in place (same rows/cols per block).
__global__ __launch_bounds__(256) void k_attn(const u16* __restrict__ KT,
                                              const u16* __restrict__ VT,
                                              u16* __restrict__ QB)
{
  __shared__ u16 sK[96 * 72];       // [key][d], padded 64->72
  __shared__ u16 sV[64 * 104];      // [d][key], padded 96->104
  __shared__ u16 sP[4][32 * 104];   // per-wave P [row][key], padded

  const int bid = blockIdx.x;
  const int h = bid & 15, b = (bid >> 4) & 15, blk = bid >> 8;
  const int t = threadIdx.x;

  const u16* gK = KT + (size_t)(b * 16 + h) * (96 * 64);
  const u16* gV = VT + (size_t)(b * 16 + h) * (64 * 96);
#pragma unroll
  for (int c = 0; c < 3; ++c) {
    int e = t * 8 + c * 2048;
    { int row = e >> 6, col = e & 63;
      *(u16x8*)&sK[row * 72 + col] = *(const u16x8*)&gK[e]; }
    { int row = e / 96, col = e - (e / 96) * 96;
      *(u16x8*)&sV[row * 104 + col] = *(const u16x8*)&gV[e]; }
  }
  __syncthreads();

  const int l = t & 63, w = t >> 6, lr = l & 15, lg = l >> 4;
  const size_t rowbase = (size_t)b * 4096 + blk * 128 + w * 32;

  // q A-frags: rows rowbase + mt*16 + lr, k = ks*32 + lg*8
  bf16x8 aq[2][2];
#pragma unroll
  for (int mt = 0; mt < 2; ++mt)
#pragma unroll
    for (int ks = 0; ks < 2; ++ks)
      aq[mt][ks] = *(const bf16x8*)&QB[(rowbase + mt * 16 + lr) * 1024 + h * 64 + ks * 32 + lg * 8];

  // scores: [32 rows][80 keys]
  f32x4 s_[2][5] = {};
#pragma unroll
  for (int nt = 0; nt < 5; ++nt) {
#pragma unroll
    for (int ks = 0; ks < 2; ++ks) {
      bf16x8 bk = *(const bf16x8*)&sK[(nt * 16 + lr) * 72 + ks * 32 + lg * 8];
#pragma unroll
      for (int mt = 0; mt < 2; ++mt)
        s_[mt][nt] = __builtin_amdgcn_mfma_f32_16x16x32_bf16(aq[mt][ks], bk, s_[mt][nt], 0, 0, 0);
    }
  }
  // scale + mask (keys 77..79 live in nt=4, lr>=13)
#pragma unroll
  for (int mt = 0; mt < 2; ++mt)
#pragma unroll
    for (int nt = 0; nt < 5; ++nt)
#pragma unroll
      for (int r = 0; r < 4; ++r)
        s_[mt][nt][r] *= 0.125f;
  if (lr >= 13) {
#pragma unroll
    for (int mt = 0; mt < 2; ++mt)
#pragma unroll
      for (int r = 0; r < 4; ++r)
        s_[mt][4][r] = -1e30f;
  }

  // softmax per row (row = mt*16 + lg*4 + r; reduce across 16 lanes lr)
  float ri[2][4];
#pragma unroll
  for (int mt = 0; mt < 2; ++mt) {
#pragma unroll
    for (int r = 0; r < 4; ++r) {
      float m1 = s_[mt][0][r];
#pragma unroll
      for (int nt = 1; nt < 5; ++nt) m1 = fmaxf(m1, s_[mt][nt][r]);
      m1 = fmaxf(m1, __shfl_xor(m1, 1, 64));
      m1 = fmaxf(m1, __shfl_xor(m1, 2, 64));
      m1 = fmaxf(m1, __shfl_xor(m1, 4, 64));
      m1 = fmaxf(m1, __shfl_xor(m1, 8, 64));
      float s1 = 0.f;
#pragma unroll
      for (int nt = 0; nt < 5; ++nt) {
        float e = __expf(s_[mt][nt][r] - m1);
        s_[mt][nt][r] = e;
        s1 += e;
      }
      s1 += __shfl_xor(s1, 1, 64);
      s1 += __shfl_xor(s1, 2, 64);
      s1 += __shfl_xor(s1, 4, 64);
      s1 += __shfl_xor(s1, 8, 64);
      ri[mt][r] = 1.0f / s1;
    }
  }

  // write P to LDS [row][key] + zero pad keys 80..95
#pragma unroll
  for (int mt = 0; mt < 2; ++mt)
#pragma unroll
    for (int nt = 0; nt < 5; ++nt)
#pragma unroll
      for (int r = 0; r < 4; ++r)
        sP[w][(mt * 16 + lg * 4 + r) * 104 + nt * 16 + lr] = f2bf(s_[mt][nt][r] * ri[mt][r]);
#pragma unroll
  for (int mt = 0; mt < 2; ++mt)
#pragma unroll
    for (int r = 0; r < 4; ++r)
      sP[w][(mt * 16 + lg * 4 + r) * 104 + 80 + lr] = 0;

  // PV: [32 rows][64 d] over 96 keys
  f32x4 o_[2][4] = {};
#pragma unroll
  for (int ks = 0; ks < 3; ++ks) {
    bf16x8 ap[2];
#pragma unroll
    for (int mt = 0; mt < 2; ++mt)
      ap[mt] = *(const bf16x8*)&sP[w][(mt * 16 + lr) * 104 + ks * 32 + lg * 8];
#pragma unroll
    for (int nt = 0; nt < 4; ++nt) {
      bf16x8 bv = *(const bf16x8*)&sV[(nt * 16 + lr) * 104 + ks * 32 + lg * 8];
#pragma unroll
      for (int mt = 0; mt < 2; ++mt)
        o_[mt][nt] = __builtin_amdgcn_mfma_f32_16x16x32_bf16(ap[mt], bv, o_[mt][nt], 0, 0, 0);
    }
  }

  // in-place write over QB (same rows/cols this block read)
#pragma unroll
  for (int mt = 0; mt < 2; ++mt)
#pragma unroll
    for (int nt = 0; nt < 4; ++nt)
#pragma unroll
      for (int r = 0; r < 4; ++r)
        QB[(rowbase + mt * 16 + lg * 4 + r) * 1024 + h * 64 + nt * 16 + lr] = f2bf(o_[mt][nt][r]);
}

// ---------------- launch ----------------

extern "C" void kernel_launch(void* const* d_in, const int* in_sizes, int n_in,
                              void* d_out, int out_size, void* d_ws, size_t ws_size,
                              hipStream_t stream) {
  const float* x  = (const float*)d_in[0];
  const float* y  = (const float*)d_in[1];
  const float* wq = (const float*)d_in[2];
  const float* bq = (const float*)d_in[3];
  const float* wk = (const float*)d_in[4];
  const float* bk = (const float*)d_in[5];
  const float* wv = (const float*)d_in[6];
  const float* bv = (const float*)d_in[7];
  const float* wo = (const float*)d_in[8];
  const float* bo = (const float*)d_in[9];

  char* ws = (char*)d_ws;
  u16* QB   = (u16*)(ws + 0);            // 65536x1024 bf16 = 128 MB (Q, then attn out in-place)
  u16* WQ2T = (u16*)(ws + 134217728);    // [1024][2048] bf16, 4 MB
  u16* WO2T = (u16*)(ws + 138412032);    // 4 MB
  u16* WK2T = (u16*)(ws + 142606336);    // [1024][1536] bf16, 3 MB
  u16* WV2T = (u16*)(ws + 145752064);    // 3 MB
  u16* YB   = (u16*)(ws + 148897792);    // [1232][1536] bf16, 3.7 MB
  u16* KT   = (u16*)(ws + 152682496);    // [16][16][96][64] bf16, 3 MB
  u16* VT   = (u16*)(ws + 155828224);    // [16][16][64][96] bf16, 3 MB

  u16*   XB  = (u16*)d_out;   // x as bf16, first 128 MB of d_out (consumed before final write)
  float* OUT = (float*)d_out;

  // prep
  k_zero<<<768, 256, 0, stream>>>((u16x8*)KT, 786432);          // zero KT+VT (adjacent)
  k_cvt_x<<<4096, 256, 0, stream>>>(x, XB, 16777216);
  k_split_w<<<2048, 256, 0, stream>>>(wq, WQ2T, 1024, 1024);
  k_split_w<<<2048, 256, 0, stream>>>(wo, WO2T, 1024, 1024);
  k_split_w<<<1536, 256, 0, stream>>>(wk, WK2T, 768, 1024);
  k_split_w<<<1536, 256, 0, stream>>>(wv, WV2T, 768, 1024);
  k_prep_y<<<2048, 256, 0, stream>>>(y, YB);

  // K/V projections: M=1232 (=16*77), K=1536 (768 hi + 768 lo), grid 10x8
  gemm_bf16<2><<<80, 256, 0, stream>>>(YB, WK2T, bk, KT, 1232, 1536, 1536, -1);
  gemm_bf16<3><<<80, 256, 0, stream>>>(YB, WV2T, bv, VT, 1232, 1536, 1536, -1);

  // Q projection: M=65536, K=2048 (1024 hi + 1024 lo), A k wraps with &1023
  gemm_bf16<0><<<4096, 256, 0, stream>>>(XB, WQ2T, bq, QB, 65536, 2048, 1024, 1023);

  // fused attention, in-place QB -> attn_out
  k_attn<<<8192, 256, 0, stream>>>(KT, VT, QB);

  // output projection -> f32 d_out
  gemm_bf16<1><<<4096, 256, 0, stream>>>(QB, WO2T, bo, OUT, 65536, 2048, 1024, 1023);
}

// Round 2
// 659.991 us; speedup vs baseline: 1.5255x; 1.5255x over previous
//
#include <hip/hip_runtime.h>

typedef unsigned short u16;
typedef __attribute__((ext_vector_type(4))) float f32x4;
typedef __attribute__((ext_vector_type(8))) short bf16x8;
typedef __attribute__((ext_vector_type(8))) unsigned short u16x8;
typedef __attribute__((ext_vector_type(4))) unsigned short u16x4;

__device__ __forceinline__ u16 f2bf(float f) {
  union { float f; unsigned u; } v; v.f = f;
  unsigned r = v.u + 0x7FFFu + ((v.u >> 16) & 1u);
  return (u16)(r >> 16);
}
__device__ __forceinline__ float bf2f(u16 h) {
  union { unsigned u; float f; } v; v.u = ((unsigned)h) << 16; return v.f;
}

__device__ __forceinline__ void gload_lds16(const void* g, void* l) {
  __builtin_amdgcn_global_load_lds((const __attribute__((address_space(1))) void*)g,
                                   (__attribute__((address_space(3))) void*)l, 16, 0, 0);
}

// ---------------- prep kernels ----------------

__global__ void k_zero(u16x8* __restrict__ p, int n8) {
  int i = blockIdx.x * blockDim.x + threadIdx.x;
  int stride = gridDim.x * blockDim.x;
  u16x8 z = (u16x8)0;
  for (; i < n8; i += stride) p[i] = z;
}

__global__ void k_cvt_x(const float* __restrict__ in, u16* __restrict__ out, int n4) {
  int i = blockIdx.x * blockDim.x + threadIdx.x;
  int stride = gridDim.x * blockDim.x;
  const f32x4* in4 = (const f32x4*)in;
  u16x4* out4 = (u16x4*)out;
  for (; i < n4; i += stride) {
    f32x4 v = in4[i];
    u16x4 o;
    o[0] = f2bf(v[0]); o[1] = f2bf(v[1]); o[2] = f2bf(v[2]); o[3] = f2bf(v[3]);
    out4[i] = o;
  }
}

// w [K][N] f32 -> outT [N][K] bf16 (plain transpose)
__global__ void k_wt(const float* __restrict__ w, u16* __restrict__ outT, int K, int N) {
  int i = blockIdx.x * blockDim.x + threadIdx.x;
  int total = K * N;
  int stride = gridDim.x * blockDim.x;
  for (; i < total; i += stride) {
    int k = i / N, n = i - k * N;
    outT[(size_t)n * K + k] = f2bf(w[i]);
  }
}

// w [K][N] f32 -> outT [N][2K] bf16: rows n, cols 0..K-1 = hi, K..2K-1 = lo
__global__ void k_split_w(const float* __restrict__ w, u16* __restrict__ outT, int K, int N) {
  int i = blockIdx.x * blockDim.x + threadIdx.x;
  int total = K * N;
  int stride = gridDim.x * blockDim.x;
  for (; i < total; i += stride) {
    int k = i / N, n = i - k * N;
    float f = w[i];
    u16 hi = f2bf(f);
    u16 lo = f2bf(f - bf2f(hi));
    size_t o = (size_t)n * (2 * K) + k;
    outT[o] = hi;
    outT[o + K] = lo;
  }
}

// y [1232][768] f32 -> yb [1232][1536] bf16 (columns duplicated)
__global__ void k_prep_y(const float* __restrict__ y, u16* __restrict__ yb) {
  int i = blockIdx.x * blockDim.x + threadIdx.x;
  int total = 1232 * 1536;
  int stride = gridDim.x * blockDim.x;
  for (; i < total; i += stride) {
    int m = i / 1536, k = i - m * 1536;
    int ks = (k < 768) ? k : k - 768;
    yb[i] = f2bf(y[m * 768 + ks]);
  }
}

// ---------------- main GEMM ----------------
// C[m,n] = sum_k A[m,k] * B[n][k]  (B pre-transposed [N=1024][Kdim])
// EPI 0: +bias, bf16 -> out[m*1024+n]        (Q projection)
// EPI 1: +bias, f32  -> out[m*1024+n]        (final output)
// EPI 2: +bias, bf16 -> KT[b][h][96 s][64 d] (K, natural, m=b*77+s, n=h*64+d)
// EPI 3: +bias, bf16 -> VT[b][h][64 d][96 s] (V, transposed)
template <int EPI>
__global__ __launch_bounds__(256, 2) void gemm_bf16(
    const u16* __restrict__ A, const u16* __restrict__ B,
    const float* __restrict__ bias, void* __restrict__ outp,
    int M, int Kdim)
{
  __shared__ u16 sA[128 * 32];
  __shared__ u16 sB[128 * 32];
  const int t = threadIdx.x;
  const int ntiles = 8; // N = 1024
  // XCD-aware bijective swizzle (gridDim.x % 8 == 0 for all our launches):
  // XCD x owns a contiguous swz-range -> contiguous bm range -> A-panel L2 reuse.
  const int cpx = gridDim.x >> 3;
  const int swz = (blockIdx.x & 7) * cpx + (blockIdx.x >> 3);
  const int bm = swz / ntiles, bn = swz % ntiles;
  const int m0 = bm * 128, n0 = bn * 128;
  const int l = t & 63, wv_ = t >> 6;
  const int lr = l & 15, lg = l >> 4;
  const int wm = (wv_ >> 1) * 64, wn = (wv_ & 1) * 64;

  // staging geometry: thread t covers LDS linear bytes t*16 (+ issue*4096)
  const int srow = t >> 2;                              // row within 64-row half
  const int ssw = ((t >> 2) & 3) ^ ((t >> 4) & 3);      // slot swizzle
  const int scol = ((t & 3) ^ ssw) * 8;                 // swizzled k-element offset
  char* ldsA = (char*)sA;
  char* ldsB = (char*)sB;
  const int ldsoff = wv_ * 1024;                        // wave-uniform base

  // read-side swizzle
  const int swl = (lr & 3) ^ ((lr >> 2) & 3);
  const int rds = (lg ^ swl) * 8;

  f32x4 acc[4][4] = {};

  const int kiter = Kdim / 32;
  for (int kt = 0; kt < kiter; ++kt) {
    const int k0 = kt * 32;
    __syncthreads();
    {
      int r1 = m0 + srow;       if (r1 > M - 1) r1 = M - 1;
      int r2 = m0 + 64 + srow;  if (r2 > M - 1) r2 = M - 1;
      gload_lds16(A + (size_t)r1 * Kdim + k0 + scol, ldsA + 0    + ldsoff);
      gload_lds16(A + (size_t)r2 * Kdim + k0 + scol, ldsA + 4096 + ldsoff);
      gload_lds16(B + (size_t)(n0 + srow) * Kdim + k0 + scol,      ldsB + 0    + ldsoff);
      gload_lds16(B + (size_t)(n0 + 64 + srow) * Kdim + k0 + scol, ldsB + 4096 + ldsoff);
    }
    __syncthreads();
    bf16x8 af[4], bf[4];
#pragma unroll
    for (int mt = 0; mt < 4; ++mt)
      af[mt] = *(const bf16x8*)&sA[(wm + mt * 16 + lr) * 32 + rds];
#pragma unroll
    for (int nt = 0; nt < 4; ++nt)
      bf[nt] = *(const bf16x8*)&sB[(wn + nt * 16 + lr) * 32 + rds];
#pragma unroll
    for (int mt = 0; mt < 4; ++mt)
#pragma unroll
      for (int nt = 0; nt < 4; ++nt)
        acc[mt][nt] = __builtin_amdgcn_mfma_f32_16x16x32_bf16(af[mt], bf[nt], acc[mt][nt], 0, 0, 0);
  }

  // epilogue: C row = wm+mt*16+lg*4+r, col = wn+nt*16+lr
#pragma unroll
  for (int mt = 0; mt < 4; ++mt) {
#pragma unroll
    for (int nt = 0; nt < 4; ++nt) {
      const int gc = n0 + wn + nt * 16 + lr;
      const float bb = bias[gc];
#pragma unroll
      for (int r = 0; r < 4; ++r) {
        const int gr = m0 + wm + mt * 16 + lg * 4 + r;
        const float v = acc[mt][nt][r] + bb;
        if constexpr (EPI == 0) {
          ((u16*)outp)[(size_t)gr * 1024 + gc] = f2bf(v);
        } else if constexpr (EPI == 1) {
          ((float*)outp)[(size_t)gr * 1024 + gc] = v;
        } else if constexpr (EPI == 2) {
          if (gr < M) {
            int bb2 = gr / 77, s = gr - bb2 * 77;
            int hh = gc >> 6, d = gc & 63;
            ((u16*)outp)[(((size_t)bb2 * 16 + hh) * 96 + s) * 64 + d] = f2bf(v);
          }
        } else {
          if (gr < M) {
            int bb2 = gr / 77, s = gr - bb2 * 77;
            int hh = gc >> 6, d = gc & 63;
            ((u16*)outp)[(((size_t)bb2 * 16 + hh) * 64 + d) * 96 + s] = f2bf(v);
          }
        }
      }
    }
  }
}

// ---------------- fused attention ----------------
// KT [B][H][96 s][64 d] bf16 (rows>=77 zero), VT [B][H][64 d][96 s] bf16 (cols>=77 zero)
// QB [65536][1024] bf16: read q, write attn-out in place (same rows/cols per block).
__global__ __launch_bounds__(256) void k_attn(const u16* __restrict__ KT,
                                              const u16* __restrict__ VT,
                                              u16* __restrict__ QB)
{
  __shared__ u16 sK[96 * 72];       // [key][d], padded 64->72
  __shared__ u16 sV[64 * 104];      // [d][key], padded 96->104
  __shared__ u16 sP[4][32 * 104];   // per-wave P [row][key], padded

  const int bid = blockIdx.x;
  const int h = bid & 15, b = (bid >> 4) & 15, blk = bid >> 8;
  const int t = threadIdx.x;

  const u16* gK = KT + (size_t)(b * 16 + h) * (96 * 64);
  const u16* gV = VT + (size_t)(b * 16 + h) * (64 * 96);
#pragma unroll
  for (int c = 0; c < 3; ++c) {
    int e = t * 8 + c * 2048;
    { int row = e >> 6, col = e & 63;
      *(u16x8*)&sK[row * 72 + col] = *(const u16x8*)&gK[e]; }
    { int row = e / 96, col = e - (e / 96) * 96;
      *(u16x8*)&sV[row * 104 + col] = *(const u16x8*)&gV[e]; }
  }
  __syncthreads();

  const int l = t & 63, w = t >> 6, lr = l & 15, lg = l >> 4;
  const size_t rowbase = (size_t)b * 4096 + blk * 128 + w * 32;

  // q A-frags: rows rowbase + mt*16 + lr, k = ks*32 + lg*8
  bf16x8 aq[2][2];
#pragma unroll
  for (int mt = 0; mt < 2; ++mt)
#pragma unroll
    for (int ks = 0; ks < 2; ++ks)
      aq[mt][ks] = *(const bf16x8*)&QB[(rowbase + mt * 16 + lr) * 1024 + h * 64 + ks * 32 + lg * 8];

  // scores: [32 rows][80 keys]
  f32x4 s_[2][5] = {};
#pragma unroll
  for (int nt = 0; nt < 5; ++nt) {
#pragma unroll
    for (int ks = 0; ks < 2; ++ks) {
      bf16x8 bk = *(const bf16x8*)&sK[(nt * 16 + lr) * 72 + ks * 32 + lg * 8];
#pragma unroll
      for (int mt = 0; mt < 2; ++mt)
        s_[mt][nt] = __builtin_amdgcn_mfma_f32_16x16x32_bf16(aq[mt][ks], bk, s_[mt][nt], 0, 0, 0);
    }
  }
  // scale + mask (keys 77..79 live in nt=4, lr>=13)
#pragma unroll
  for (int mt = 0; mt < 2; ++mt)
#pragma unroll
    for (int nt = 0; nt < 5; ++nt)
#pragma unroll
      for (int r = 0; r < 4; ++r)
        s_[mt][nt][r] *= 0.125f;
  if (lr >= 13) {
#pragma unroll
    for (int mt = 0; mt < 2; ++mt)
#pragma unroll
      for (int r = 0; r < 4; ++r)
        s_[mt][4][r] = -1e30f;
  }

  // softmax per row (row = mt*16 + lg*4 + r; reduce across 16 lanes lr)
  float ri[2][4];
#pragma unroll
  for (int mt = 0; mt < 2; ++mt) {
#pragma unroll
    for (int r = 0; r < 4; ++r) {
      float m1 = s_[mt][0][r];
#pragma unroll
      for (int nt = 1; nt < 5; ++nt) m1 = fmaxf(m1, s_[mt][nt][r]);
      m1 = fmaxf(m1, __shfl_xor(m1, 1, 64));
      m1 = fmaxf(m1, __shfl_xor(m1, 2, 64));
      m1 = fmaxf(m1, __shfl_xor(m1, 4, 64));
      m1 = fmaxf(m1, __shfl_xor(m1, 8, 64));
      float s1 = 0.f;
#pragma unroll
      for (int nt = 0; nt < 5; ++nt) {
        float e = __expf(s_[mt][nt][r] - m1);
        s_[mt][nt][r] = e;
        s1 += e;
      }
      s1 += __shfl_xor(s1, 1, 64);
      s1 += __shfl_xor(s1, 2, 64);
      s1 += __shfl_xor(s1, 4, 64);
      s1 += __shfl_xor(s1, 8, 64);
      ri[mt][r] = 1.0f / s1;
    }
  }

  // write P to LDS [row][key] + zero pad keys 80..95
#pragma unroll
  for (int mt = 0; mt < 2; ++mt)
#pragma unroll
    for (int nt = 0; nt < 5; ++nt)
#pragma unroll
      for (int r = 0; r < 4; ++r)
        sP[w][(mt * 16 + lg * 4 + r) * 104 + nt * 16 + lr] = f2bf(s_[mt][nt][r] * ri[mt][r]);
#pragma unroll
  for (int mt = 0; mt < 2; ++mt)
#pragma unroll
    for (int r = 0; r < 4; ++r)
      sP[w][(mt * 16 + lg * 4 + r) * 104 + 80 + lr] = 0;

  // PV: [32 rows][64 d] over 96 keys
  f32x4 o_[2][4] = {};
#pragma unroll
  for (int ks = 0; ks < 3; ++ks) {
    bf16x8 ap[2];
#pragma unroll
    for (int mt = 0; mt < 2; ++mt)
      ap[mt] = *(const bf16x8*)&sP[w][(mt * 16 + lr) * 104 + ks * 32 + lg * 8];
#pragma unroll
    for (int nt = 0; nt < 4; ++nt) {
      bf16x8 bv = *(const bf16x8*)&sV[(nt * 16 + lr) * 104 + ks * 32 + lg * 8];
#pragma unroll
      for (int mt = 0; mt < 2; ++mt)
        o_[mt][nt] = __builtin_amdgcn_mfma_f32_16x16x32_bf16(ap[mt], bv, o_[mt][nt], 0, 0, 0);
    }
  }

  // in-place write over QB (same rows/cols this block read)
#pragma unroll
  for (int mt = 0; mt < 2; ++mt)
#pragma unroll
    for (int nt = 0; nt < 4; ++nt)
#pragma unroll
      for (int r = 0; r < 4; ++r)
        QB[(rowbase + mt * 16 + lg * 4 + r) * 1024 + h * 64 + nt * 16 + lr] = f2bf(o_[mt][nt][r]);
}

// ---------------- launch ----------------

extern "C" void kernel_launch(void* const* d_in, const int* in_sizes, int n_in,
                              void* d_out, int out_size, void* d_ws, size_t ws_size,
                              hipStream_t stream) {
  const float* x  = (const float*)d_in[0];
  const float* y  = (const float*)d_in[1];
  const float* wq = (const float*)d_in[2];
  const float* bq = (const float*)d_in[3];
  const float* wk = (const float*)d_in[4];
  const float* bk = (const float*)d_in[5];
  const float* wv = (const float*)d_in[6];
  const float* bv = (const float*)d_in[7];
  const float* wo = (const float*)d_in[8];
  const float* bo = (const float*)d_in[9];

  char* ws = (char*)d_ws;
  u16* QB   = (u16*)(ws + 0);            // 65536x1024 bf16 = 128 MB (Q, then attn out in-place)
  u16* WQ1T = (u16*)(ws + 134217728);    // [1024][1024] bf16, 2 MB
  u16* WO1T = (u16*)(ws + 136314880);    // 2 MB
  u16* WK2T = (u16*)(ws + 138412032);    // [1024][1536] bf16, 3 MB
  u16* WV2T = (u16*)(ws + 141557760);    // 3 MB
  u16* YB   = (u16*)(ws + 144703488);    // [1232][1536] bf16, 3.7 MB
  u16* KT   = (u16*)(ws + 148488192);    // [16][16][96][64] bf16, 3 MB
  u16* VT   = (u16*)(ws + 151633920);    // [16][16][64][96] bf16, 3 MB

  u16*   XB  = (u16*)d_out;   // x as bf16, first 128 MB of d_out (consumed before final write)
  float* OUT = (float*)d_out;

  // prep
  k_zero<<<768, 256, 0, stream>>>((u16x8*)KT, 786432);          // zero KT+VT (adjacent)
  k_cvt_x<<<4096, 256, 0, stream>>>(x, XB, 16777216);
  k_wt<<<2048, 256, 0, stream>>>(wq, WQ1T, 1024, 1024);
  k_wt<<<2048, 256, 0, stream>>>(wo, WO1T, 1024, 1024);
  k_split_w<<<1536, 256, 0, stream>>>(wk, WK2T, 768, 1024);
  k_split_w<<<1536, 256, 0, stream>>>(wv, WV2T, 768, 1024);
  k_prep_y<<<2048, 256, 0, stream>>>(y, YB);

  // K/V projections: M=1232 (=16*77), K=1536 (768 hi + 768 lo), grid 10x8
  gemm_bf16<2><<<80, 256, 0, stream>>>(YB, WK2T, bk, KT, 1232, 1536);
  gemm_bf16<3><<<80, 256, 0, stream>>>(YB, WV2T, bv, VT, 1232, 1536);

  // Q projection: M=65536, K=1024
  gemm_bf16<0><<<4096, 256, 0, stream>>>(XB, WQ1T, bq, QB, 65536, 1024);

  // fused attention, in-place QB -> attn_out
  k_attn<<<8192, 256, 0, stream>>>(KT, VT, QB);

  // output projection -> f32 d_out
  gemm_bf16<1><<<4096, 256, 0, stream>>>(QB, WO1T, bo, OUT, 65536, 1024);
}